// Round 3
// baseline (614.524 us; speedup 1.0000x reference)
//
#include <hip/hip_runtime.h>
#include <math.h>

#define BB 8
#define PP 57744
#define NOBJ 20
#define CC 81
#define ROWS (BB*PP)
#define RPB 64                    // rows per tile in k_conf
#define NT (ROWS/RPB)             // 7218 tiles
#define NV (RPB*CC/4)             // 1296 float4 per tile
#define CONF_GRID 1792            // 7 blocks/CU persistent
#define SEL_GRID 256              // <= #CUs: guaranteed co-resident for grid barrier
#define BPSPLIT 16
#define BPCHUNK ((PP + BPSPLIT - 1) / BPSPLIT)   // 3609

// ws layout in 4-byte units (first 8KB zeroed by memset)
// cnt_i: [0]=num_pos [1]=sl1_sum(f) [2]=pos_ce(f) [3]=neg_ce(f) [4]=neg_cnt [5]=eqCtr
//        [8]=prefix [9]=Kr [10]=T [11]=eqSlots [32]=bar_cnt [33]=bar_gen
#define W_HIST 64     // 4*256 bins
#define W_BP   1088   // 160 u64
#define W_CONF 2048           // ROWS ints
#define W_KEY  (2048 + ROWS)  // ROWS uints
#define W_CE   (2048 + 2*ROWS)// ROWS floats

__device__ __forceinline__ unsigned keymap(float f) {
    unsigned u = __float_as_uint(f);
    return (u & 0x80000000u) ? ~u : (u | 0x80000000u);
}

__device__ __forceinline__ float smooth_l1(float d) {
    float a = fabsf(d);
    return a < 1.f ? 0.5f * d * d : a - 0.5f;
}

// ---------- grid barrier (all blocks co-resident: grid <= 256 CUs) ----------
__device__ __forceinline__ void grid_bar(int* cnt, int* gen) {
    __syncthreads();
    if (threadIdx.x == 0) {
        int g = __hip_atomic_load(gen, __ATOMIC_RELAXED, __HIP_MEMORY_SCOPE_AGENT);
        __threadfence();
        if (atomicAdd(cnt, 1) == (int)gridDim.x - 1) {
            __hip_atomic_store(cnt, 0, __ATOMIC_RELAXED, __HIP_MEMORY_SCOPE_AGENT);
            __hip_atomic_store(gen, g + 1, __ATOMIC_RELEASE, __HIP_MEMORY_SCOPE_AGENT);
        } else {
            while (__hip_atomic_load(gen, __ATOMIC_ACQUIRE, __HIP_MEMORY_SCOPE_AGENT) == g)
                __builtin_amdgcn_s_sleep(8);
        }
    }
    __syncthreads();
}

// Grid (NOBJ, BB, BPSPLIT): per-(gt,batch) argmax over prior chunk, packed
// (iou_bits<<32)|(~p): u64 max == (max iou, lowest prior idx). IoU >= 0.
__global__ void k_best_prior(const float* __restrict__ priors,
                             const float* __restrict__ gt,
                             unsigned long long* __restrict__ bp) {
    int n = blockIdx.x, b = blockIdx.y;
    int p0 = blockIdx.z * BPCHUNK;
    int p1 = min(p0 + BPCHUNK, PP);
    const float* t = gt + (b * NOBJ + n) * 4;
    float tx1 = t[0], ty1 = t[1], tx2 = t[2], ty2 = t[3];
    float ta = (tx2 - tx1) * (ty2 - ty1);
    unsigned long long best = 0ull;
    for (int p = p0 + threadIdx.x; p < p1; p += 256) {
        float4 pr = ((const float4*)priors)[p];
        float px1 = pr.x - pr.z * 0.5f, py1 = pr.y - pr.w * 0.5f;
        float px2 = pr.x + pr.z * 0.5f, py2 = pr.y + pr.w * 0.5f;
        float iw = fmaxf(fminf(tx2, px2) - fmaxf(tx1, px1), 0.f);
        float ih = fmaxf(fminf(ty2, py2) - fmaxf(ty1, py1), 0.f);
        float inter = iw * ih;
        float iou = inter / (ta + (px2 - px1) * (py2 - py1) - inter);
        unsigned long long pk = ((unsigned long long)__float_as_uint(iou) << 32)
                              | (unsigned long long)(0xFFFFFFFFu - (unsigned)p);
        if (pk > best) best = pk;
    }
    __shared__ unsigned long long sb[256];
    int tid = threadIdx.x;
    sb[tid] = best; __syncthreads();
    for (int s = 128; s > 0; s >>= 1) {
        if (tid < s && sb[tid + s] > sb[tid]) sb[tid] = sb[tid + s];
        __syncthreads();
    }
    if (tid == 0) atomicMax(&bp[b * NOBJ + n], sb[0]);
}

__global__ void k_match(const float* __restrict__ loc_data,
                        const float* __restrict__ priors,
                        const float* __restrict__ gt,
                        const int* __restrict__ labels,
                        const unsigned long long* __restrict__ bp,
                        int* __restrict__ conf_t,
                        float* __restrict__ cnt_f,
                        int* __restrict__ cnt_i) {
    int b = blockIdx.y;
    int tid = threadIdx.x;
    int p = blockIdx.x * 256 + tid;
    __shared__ float st[NOBJ][4];
    __shared__ int slab[NOBJ], sbp[NOBJ];
    if (tid < NOBJ * 4) ((float*)st)[tid] = gt[b * NOBJ * 4 + tid];
    if (tid < NOBJ) {
        slab[tid] = labels[b * NOBJ + tid];
        sbp[tid] = (int)(0xFFFFFFFFu - (unsigned)bp[b * NOBJ + tid]);
    }
    __syncthreads();
    float s_l1 = 0.f; int is_pos = 0;
    if (p < PP) {
        float4 pr = ((const float4*)priors)[p];
        float px1 = pr.x - pr.z * 0.5f, py1 = pr.y - pr.w * 0.5f;
        float px2 = pr.x + pr.z * 0.5f, py2 = pr.y + pr.w * 0.5f;
        float pa = (px2 - px1) * (py2 - py1);
        float best = -1.f; int bn = 0;
        for (int n = 0; n < NOBJ; n++) {
            float tx1 = st[n][0], ty1 = st[n][1], tx2 = st[n][2], ty2 = st[n][3];
            float iw = fmaxf(fminf(tx2, px2) - fmaxf(tx1, px1), 0.f);
            float ih = fmaxf(fminf(ty2, py2) - fmaxf(ty1, py1), 0.f);
            float inter = iw * ih;
            float iou = inter / ((tx2 - tx1) * (ty2 - ty1) + pa - inter);
            if (iou > best) { best = iou; bn = n; }  // tie -> first n
        }
        float ov = best;
        for (int n = 0; n < NOBJ; n++)
            if (sbp[n] == p) { bn = n; ov = 2.0f; }  // last n wins
        int conf = slab[bn];
        if (ov < 0.5f) conf = -1;
        if (ov < 0.4f) conf = 0;
        conf_t[b * PP + p] = conf;
        if (conf > 0) {
            is_pos = 1;
            float mx1 = st[bn][0], my1 = st[bn][1], mx2 = st[bn][2], my2 = st[bn][3];
            float gcx = ((mx1 + mx2) * 0.5f - pr.x) / (0.1f * pr.z);
            float gcy = ((my1 + my2) * 0.5f - pr.y) / (0.1f * pr.w);
            float gw = logf((mx2 - mx1) / pr.z) / 0.2f;
            float gh = logf((my2 - my1) / pr.w) / 0.2f;
            float4 ld = ((const float4*)loc_data)[b * PP + p];
            s_l1 = smooth_l1(ld.x - gcx) + smooth_l1(ld.y - gcy) +
                   smooth_l1(ld.z - gw) + smooth_l1(ld.w - gh);
        }
    }
    __shared__ float rs[256]; __shared__ int rc[256];
    rs[tid] = s_l1; rc[tid] = is_pos; __syncthreads();
    for (int s = 128; s > 0; s >>= 1) {
        if (tid < s) { rs[tid] += rs[tid + s]; rc[tid] += rc[tid + s]; }
        __syncthreads();
    }
    if (tid == 0) {
        if (rs[0] != 0.f) atomicAdd(&cnt_f[1], rs[0]);
        if (rc[0])        atomicAdd(&cnt_i[0], rc[0]);
    }
}

// Persistent pipelined conf pass: each block grid-strides over 64-row tiles.
// Tile t+1's global loads are fired into registers before computing tile t
// from LDS, so loads stay in flight across the entire compute phase.
__global__ void __launch_bounds__(256) k_conf(const float* __restrict__ conf_data,
                                              const int* __restrict__ conf_t,
                                              unsigned* __restrict__ key,
                                              float* __restrict__ ce,
                                              float* __restrict__ cnt_f) {
    __shared__ float sx[RPB * CC];   // 20736 B -> 7 blocks/CU
    int tid = threadIdx.x;
    const float4* g = (const float4*)conf_data;
    float4* s4 = (float4*)sx;
    int r = tid >> 2, t = tid & 3;
    const float* x = sx + r * CC;
    const float LOG2E = 1.4426950408889634f;

    float4 rb[6];
    int tile = blockIdx.x;
    {   // prologue: load first tile into regs
        size_t base = (size_t)tile * NV;
        #pragma unroll
        for (int i = 0; i < 5; i++) rb[i] = g[base + tid + 256 * i];
        if (tid < NV - 1280) rb[5] = g[base + 1280 + tid];
    }
    for (; tile < NT; tile += CONF_GRID) {
        __syncthreads();                 // prior compute done, LDS free
        #pragma unroll
        for (int i = 0; i < 5; i++) s4[tid + 256 * i] = rb[i];
        if (tid < NV - 1280) s4[1280 + tid] = rb[5];
        __syncthreads();
        int nxt = tile + CONF_GRID;
        if (nxt < NT) {                  // fire next tile's loads (no wait)
            size_t base = (size_t)nxt * NV;
            #pragma unroll
            for (int i = 0; i < 5; i++) rb[i] = g[base + tid + 256 * i];
            if (tid < NV - 1280) rb[5] = g[base + 1280 + tid];
        }
        // ---- compute current tile from LDS ----
        int row = tile * RPB + r;
        float m = (t == 0) ? x[0] : -INFINITY;
        float fg = -INFINITY;
        for (int c = (t == 0) ? 4 : t; c < CC; c += 4) {
            float v = x[c];
            m = fmaxf(m, v);
            fg = fmaxf(fg, v);
        }
        m = fmaxf(m, __shfl_xor(m, 1));
        m = fmaxf(m, __shfl_xor(m, 2));
        fg = fmaxf(fg, __shfl_xor(fg, 1));
        fg = fmaxf(fg, __shfl_xor(fg, 2));
        float e = 0.f;
        for (int c = t; c < CC; c += 4) e += exp2f((x[c] - m) * LOG2E);
        e += __shfl_xor(e, 1);
        e += __shfl_xor(e, 2);
        if (t == 0) {
            float lse = m + log2f(e) * 0.6931471805599453f;
            int ct = conf_t[row];
            int ctc = min(max(ct, 0), CC - 1);
            float cev = lse - x[ctc];
            ce[row] = cev;
            key[row] = (ct == 0) ? keymap(fg) : 0u;
            if (ct > 0) atomicAdd(&cnt_f[2], cev);
        }
    }
}

// Fused radix-select (4x hist + scan) + negative CE sum + final, one dispatch.
__global__ void __launch_bounds__(256) k_select(const unsigned* __restrict__ key,
                                                const float* __restrict__ ce,
                                                const int* __restrict__ conf_t,
                                                int* cnt_i, float* cnt_f,
                                                unsigned* hist,
                                                float* __restrict__ out) {
    __shared__ unsigned lh[256];
    __shared__ unsigned sd[256];
    __shared__ float rs[256]; __shared__ int rc[256];
    int tid = threadIdx.x;
    int* bcnt = cnt_i + 32; int* bgen = cnt_i + 33;
    int stride = gridDim.x * 256;

    for (int s = 0; s < 4; s++) {
        lh[tid] = 0; __syncthreads();
        unsigned prefix = (s == 0) ? 0u
            : (unsigned)__hip_atomic_load(&cnt_i[8], __ATOMIC_RELAXED, __HIP_MEMORY_SCOPE_AGENT);
        int shift = 24 - 8 * s;
        for (int rr = blockIdx.x * 256 + tid; rr < ROWS; rr += stride) {
            unsigned k = key[rr];
            if (s == 0 || (k >> (shift + 8)) == prefix)
                atomicAdd(&lh[(k >> shift) & 0xffu], 1u);
        }
        __syncthreads();
        if (lh[tid]) atomicAdd(&hist[s * 256 + tid], lh[tid]);
        grid_bar(bcnt, bgen);
        if (blockIdx.x == 0) {
            sd[tid] = __hip_atomic_load(&hist[s * 256 + tid], __ATOMIC_RELAXED,
                                        __HIP_MEMORY_SCOPE_AGENT);
            __syncthreads();
            for (int off = 1; off < 256; off <<= 1) {
                unsigned add = (tid + off < 256) ? sd[tid + off] : 0u;
                __syncthreads();
                sd[tid] += add;
                __syncthreads();
            }
            unsigned Kr, pfx;
            if (s == 0) {
                Kr = 3u * (unsigned)__hip_atomic_load(&cnt_i[0], __ATOMIC_RELAXED,
                                                      __HIP_MEMORY_SCOPE_AGENT);
                pfx = 0u;
            } else {
                pfx = (unsigned)__hip_atomic_load(&cnt_i[8], __ATOMIC_RELAXED, __HIP_MEMORY_SCOPE_AGENT);
                Kr  = (unsigned)__hip_atomic_load(&cnt_i[9], __ATOMIC_RELAXED, __HIP_MEMORY_SCOPE_AGENT);
            }
            unsigned cum = sd[tid];
            unsigned upper = (tid < 255) ? sd[tid + 1] : 0u;
            bool sel = (upper < Kr) && (cum >= Kr || tid == 0);
            if (sel) {
                unsigned np = (pfx << 8) | (unsigned)tid;
                unsigned nKr = Kr - upper;
                if (s < 3) {
                    __hip_atomic_store(&cnt_i[8], (int)np,  __ATOMIC_RELAXED, __HIP_MEMORY_SCOPE_AGENT);
                    __hip_atomic_store(&cnt_i[9], (int)nKr, __ATOMIC_RELAXED, __HIP_MEMORY_SCOPE_AGENT);
                } else {
                    __hip_atomic_store(&cnt_i[10], (int)np,  __ATOMIC_RELAXED, __HIP_MEMORY_SCOPE_AGENT);
                    __hip_atomic_store(&cnt_i[11], (int)nKr, __ATOMIC_RELAXED, __HIP_MEMORY_SCOPE_AGENT);
                }
            }
        }
        grid_bar(bcnt, bgen);
    }

    // negsum: key > T, or == T up to eqSlots
    unsigned T = (unsigned)__hip_atomic_load(&cnt_i[10], __ATOMIC_RELAXED, __HIP_MEMORY_SCOPE_AGENT);
    int eqS = __hip_atomic_load(&cnt_i[11], __ATOMIC_RELAXED, __HIP_MEMORY_SCOPE_AGENT);
    float sacc = 0.f; int cacc = 0;
    for (int rr = blockIdx.x * 256 + tid; rr < ROWS; rr += stride) {
        if (conf_t[rr] == 0) {
            unsigned k = key[rr];
            if (k > T) { sacc += ce[rr]; cacc++; }
            else if (k == T) {
                int slot = atomicAdd(&cnt_i[5], 1);
                if (slot < eqS) { sacc += ce[rr]; cacc++; }
            }
        }
    }
    rs[tid] = sacc; rc[tid] = cacc; __syncthreads();
    for (int st = 128; st > 0; st >>= 1) {
        if (tid < st) { rs[tid] += rs[tid + st]; rc[tid] += rc[tid + st]; }
        __syncthreads();
    }
    if (tid == 0) {
        if (rs[0] != 0.f) atomicAdd(&cnt_f[3], rs[0]);
        if (rc[0])        atomicAdd(&cnt_i[4], rc[0]);
    }
    grid_bar(bcnt, bgen);
    if (blockIdx.x == 0 && tid == 0) {
        int np = __hip_atomic_load(&cnt_i[0], __ATOMIC_RELAXED, __HIP_MEMORY_SCOPE_AGENT);
        int nn = __hip_atomic_load(&cnt_i[4], __ATOMIC_RELAXED, __HIP_MEMORY_SCOPE_AGENT);
        float sl1 = __hip_atomic_load(&cnt_f[1], __ATOMIC_RELAXED, __HIP_MEMORY_SCOPE_AGENT);
        float pce = __hip_atomic_load(&cnt_f[2], __ATOMIC_RELAXED, __HIP_MEMORY_SCOPE_AGENT);
        float nce = __hip_atomic_load(&cnt_f[3], __ATOMIC_RELAXED, __HIP_MEMORY_SCOPE_AGENT);
        out[0] = sl1 / (float)max(np, 1);
        out[1] = (pce + nce) / (float)max(np + nn, 1);
    }
}

extern "C" void kernel_launch(void* const* d_in, const int* in_sizes, int n_in,
                              void* d_out, int out_size, void* d_ws, size_t ws_size,
                              hipStream_t stream) {
    const float* loc    = (const float*)d_in[0];
    const float* conf   = (const float*)d_in[1];
    const float* priors = (const float*)d_in[2];
    const float* gt     = (const float*)d_in[3];
    const int*   labels = (const int*)d_in[4];
    float* out = (float*)d_out;
    int*      wi = (int*)d_ws;
    float*    wf = (float*)d_ws;
    unsigned* wu = (unsigned*)d_ws;
    unsigned long long* wbp = (unsigned long long*)(wi + W_BP);

    hipMemsetAsync(d_ws, 0, 8192, stream);  // counters + hists + bp + barrier
    k_best_prior<<<dim3(NOBJ, BB, BPSPLIT), 256, 0, stream>>>(priors, gt, wbp);
    k_match<<<dim3((PP + 255) / 256, BB), 256, 0, stream>>>(
        loc, priors, gt, labels, wbp, wi + W_CONF, wf, wi);
    k_conf<<<CONF_GRID, 256, 0, stream>>>(conf, wi + W_CONF, wu + W_KEY, wf + W_CE, wf);
    k_select<<<SEL_GRID, 256, 0, stream>>>(
        wu + W_KEY, wf + W_CE, wi + W_CONF, wi, wf, wu + W_HIST, out);
}

// Round 4
// 520.535 us; speedup vs baseline: 1.1806x; 1.1806x over previous
//
#include <hip/hip_runtime.h>
#include <math.h>

#define BB 8
#define PP 57744
#define NOBJ 20
#define CC 81
#define ROWS (BB*PP)
#define RPB 64                    // rows per tile in k_conf
#define NT (ROWS/RPB)             // 7218 tiles
#define NV (RPB*CC/4)             // 1296 float4 per tile
#define CONF_GRID 1792            // 7 blocks/CU persistent
#define SEL_GRID 256              // <= #CUs: guaranteed co-resident for grid barrier
#define BPSPLIT 16
#define BPCHUNK ((PP + BPSPLIT - 1) / BPSPLIT)   // 3609

// ws layout in 4-byte units (first 8KB zeroed by memset)
// cnt_i: [0]=num_pos [1]=sl1_sum(f) [2]=pos_ce(f) [3]=neg_ce(f) [4]=neg_cnt [5]=eqCtr
//        [8]=prefix [9]=Kr [10]=T [11]=eqSlots [32]=bar_cnt [33]=bar_gen
#define W_HIST 64     // 4*256 bins
#define W_BP   1088   // 160 u64
#define W_CONF 2048           // ROWS ints
#define W_KEY  (2048 + ROWS)  // ROWS uints
#define W_CE   (2048 + 2*ROWS)// ROWS floats

#define AGENT __HIP_MEMORY_SCOPE_AGENT

__device__ __forceinline__ unsigned keymap(float f) {
    unsigned u = __float_as_uint(f);
    return (u & 0x80000000u) ? ~u : (u | 0x80000000u);
}

__device__ __forceinline__ float smooth_l1(float d) {
    float a = fabsf(d);
    return a < 1.f ? 0.5f * d * d : a - 0.5f;
}

// Grid barrier, cheap version: spin uses RELAXED agent atomic loads (coherent
// at LLC, no cache-maintenance per poll). One ACQ_REL RMW at arrival and one
// acquire fence at exit per block per barrier. All cross-barrier data flows
// through agent-scope atomics (hist/cnt), so this is sufficient.
__device__ __forceinline__ void grid_bar(int* cnt, int* gen) {
    __syncthreads();   // implies per-wave vmcnt(0): prior atomics have landed
    if (threadIdx.x == 0) {
        int g = __hip_atomic_load(gen, __ATOMIC_RELAXED, AGENT);
        int old = __hip_atomic_fetch_add(cnt, 1, __ATOMIC_ACQ_REL, AGENT);
        if (old == (int)gridDim.x - 1) {
            __hip_atomic_store(cnt, 0, __ATOMIC_RELAXED, AGENT);
            __hip_atomic_store(gen, g + 1, __ATOMIC_RELEASE, AGENT);  // orders cnt=0 first
        } else {
            while (__hip_atomic_load(gen, __ATOMIC_RELAXED, AGENT) == g)
                __builtin_amdgcn_s_sleep(2);
        }
        __builtin_amdgcn_fence(__ATOMIC_ACQUIRE, "agent");  // once per barrier
    }
    __syncthreads();
}

// Grid (NOBJ, BB, BPSPLIT): per-(gt,batch) argmax over prior chunk, packed
// (iou_bits<<32)|(~p): u64 max == (max iou, lowest prior idx). IoU >= 0.
__global__ void k_best_prior(const float* __restrict__ priors,
                             const float* __restrict__ gt,
                             unsigned long long* __restrict__ bp) {
    int n = blockIdx.x, b = blockIdx.y;
    int p0 = blockIdx.z * BPCHUNK;
    int p1 = min(p0 + BPCHUNK, PP);
    const float* t = gt + (b * NOBJ + n) * 4;
    float tx1 = t[0], ty1 = t[1], tx2 = t[2], ty2 = t[3];
    float ta = (tx2 - tx1) * (ty2 - ty1);
    unsigned long long best = 0ull;
    for (int p = p0 + threadIdx.x; p < p1; p += 256) {
        float4 pr = ((const float4*)priors)[p];
        float px1 = pr.x - pr.z * 0.5f, py1 = pr.y - pr.w * 0.5f;
        float px2 = pr.x + pr.z * 0.5f, py2 = pr.y + pr.w * 0.5f;
        float iw = fmaxf(fminf(tx2, px2) - fmaxf(tx1, px1), 0.f);
        float ih = fmaxf(fminf(ty2, py2) - fmaxf(ty1, py1), 0.f);
        float inter = iw * ih;
        float iou = inter / (ta + (px2 - px1) * (py2 - py1) - inter);
        unsigned long long pk = ((unsigned long long)__float_as_uint(iou) << 32)
                              | (unsigned long long)(0xFFFFFFFFu - (unsigned)p);
        if (pk > best) best = pk;
    }
    __shared__ unsigned long long sb[256];
    int tid = threadIdx.x;
    sb[tid] = best; __syncthreads();
    for (int s = 128; s > 0; s >>= 1) {
        if (tid < s && sb[tid + s] > sb[tid]) sb[tid] = sb[tid + s];
        __syncthreads();
    }
    if (tid == 0) atomicMax(&bp[b * NOBJ + n], sb[0]);
}

__global__ void k_match(const float* __restrict__ loc_data,
                        const float* __restrict__ priors,
                        const float* __restrict__ gt,
                        const int* __restrict__ labels,
                        const unsigned long long* __restrict__ bp,
                        int* __restrict__ conf_t,
                        float* __restrict__ cnt_f,
                        int* __restrict__ cnt_i) {
    int b = blockIdx.y;
    int tid = threadIdx.x;
    int p = blockIdx.x * 256 + tid;
    __shared__ float st[NOBJ][4];
    __shared__ int slab[NOBJ], sbp[NOBJ];
    if (tid < NOBJ * 4) ((float*)st)[tid] = gt[b * NOBJ * 4 + tid];
    if (tid < NOBJ) {
        slab[tid] = labels[b * NOBJ + tid];
        sbp[tid] = (int)(0xFFFFFFFFu - (unsigned)bp[b * NOBJ + tid]);
    }
    __syncthreads();
    float s_l1 = 0.f; int is_pos = 0;
    if (p < PP) {
        float4 pr = ((const float4*)priors)[p];
        float px1 = pr.x - pr.z * 0.5f, py1 = pr.y - pr.w * 0.5f;
        float px2 = pr.x + pr.z * 0.5f, py2 = pr.y + pr.w * 0.5f;
        float pa = (px2 - px1) * (py2 - py1);
        float best = -1.f; int bn = 0;
        for (int n = 0; n < NOBJ; n++) {
            float tx1 = st[n][0], ty1 = st[n][1], tx2 = st[n][2], ty2 = st[n][3];
            float iw = fmaxf(fminf(tx2, px2) - fmaxf(tx1, px1), 0.f);
            float ih = fmaxf(fminf(ty2, py2) - fmaxf(ty1, py1), 0.f);
            float inter = iw * ih;
            float iou = inter / ((tx2 - tx1) * (ty2 - ty1) + pa - inter);
            if (iou > best) { best = iou; bn = n; }  // tie -> first n
        }
        float ov = best;
        for (int n = 0; n < NOBJ; n++)
            if (sbp[n] == p) { bn = n; ov = 2.0f; }  // last n wins
        int conf = slab[bn];
        if (ov < 0.5f) conf = -1;
        if (ov < 0.4f) conf = 0;
        conf_t[b * PP + p] = conf;
        if (conf > 0) {
            is_pos = 1;
            float mx1 = st[bn][0], my1 = st[bn][1], mx2 = st[bn][2], my2 = st[bn][3];
            float gcx = ((mx1 + mx2) * 0.5f - pr.x) / (0.1f * pr.z);
            float gcy = ((my1 + my2) * 0.5f - pr.y) / (0.1f * pr.w);
            float gw = logf((mx2 - mx1) / pr.z) / 0.2f;
            float gh = logf((my2 - my1) / pr.w) / 0.2f;
            float4 ld = ((const float4*)loc_data)[b * PP + p];
            s_l1 = smooth_l1(ld.x - gcx) + smooth_l1(ld.y - gcy) +
                   smooth_l1(ld.z - gw) + smooth_l1(ld.w - gh);
        }
    }
    __shared__ float rs[256]; __shared__ int rc[256];
    rs[tid] = s_l1; rc[tid] = is_pos; __syncthreads();
    for (int s = 128; s > 0; s >>= 1) {
        if (tid < s) { rs[tid] += rs[tid + s]; rc[tid] += rc[tid + s]; }
        __syncthreads();
    }
    if (tid == 0) {
        if (rs[0] != 0.f) atomicAdd(&cnt_f[1], rs[0]);
        if (rc[0])        atomicAdd(&cnt_i[0], rc[0]);
    }
}

// Persistent pipelined conf pass: each block grid-strides over 64-row tiles.
// Tile t+1's global loads are fired into registers before computing tile t
// from LDS, so loads stay in flight across the entire compute phase.
__global__ void __launch_bounds__(256) k_conf(const float* __restrict__ conf_data,
                                              const int* __restrict__ conf_t,
                                              unsigned* __restrict__ key,
                                              float* __restrict__ ce,
                                              float* __restrict__ cnt_f) {
    __shared__ float sx[RPB * CC];   // 20736 B -> 7 blocks/CU
    int tid = threadIdx.x;
    const float4* g = (const float4*)conf_data;
    float4* s4 = (float4*)sx;
    int r = tid >> 2, t = tid & 3;
    const float* x = sx + r * CC;
    const float LOG2E = 1.4426950408889634f;

    float4 rb[6];
    int tile = blockIdx.x;
    {   // prologue: load first tile into regs
        size_t base = (size_t)tile * NV;
        #pragma unroll
        for (int i = 0; i < 5; i++) rb[i] = g[base + tid + 256 * i];
        if (tid < NV - 1280) rb[5] = g[base + 1280 + tid];
    }
    for (; tile < NT; tile += CONF_GRID) {
        __syncthreads();                 // prior compute done, LDS free
        #pragma unroll
        for (int i = 0; i < 5; i++) s4[tid + 256 * i] = rb[i];
        if (tid < NV - 1280) s4[1280 + tid] = rb[5];
        __syncthreads();
        int nxt = tile + CONF_GRID;
        if (nxt < NT) {                  // fire next tile's loads (no wait)
            size_t base = (size_t)nxt * NV;
            #pragma unroll
            for (int i = 0; i < 5; i++) rb[i] = g[base + tid + 256 * i];
            if (tid < NV - 1280) rb[5] = g[base + 1280 + tid];
        }
        // ---- compute current tile from LDS ----
        int row = tile * RPB + r;
        float m = (t == 0) ? x[0] : -INFINITY;
        float fg = -INFINITY;
        for (int c = (t == 0) ? 4 : t; c < CC; c += 4) {
            float v = x[c];
            m = fmaxf(m, v);
            fg = fmaxf(fg, v);
        }
        m = fmaxf(m, __shfl_xor(m, 1));
        m = fmaxf(m, __shfl_xor(m, 2));
        fg = fmaxf(fg, __shfl_xor(fg, 1));
        fg = fmaxf(fg, __shfl_xor(fg, 2));
        float e = 0.f;
        for (int c = t; c < CC; c += 4) e += exp2f((x[c] - m) * LOG2E);
        e += __shfl_xor(e, 1);
        e += __shfl_xor(e, 2);
        if (t == 0) {
            float lse = m + log2f(e) * 0.6931471805599453f;
            int ct = conf_t[row];
            int ctc = min(max(ct, 0), CC - 1);
            float cev = lse - x[ctc];
            ce[row] = cev;
            key[row] = (ct == 0) ? keymap(fg) : 0u;
            if (ct > 0) atomicAdd(&cnt_f[2], cev);
        }
    }
}

// Fused radix-select (4x hist+scan, 8-bit digits, LDS-privatized histograms)
// + negative CE sum + final. One dispatch, 9 cheap grid barriers.
__global__ void __launch_bounds__(256) k_select(const unsigned* __restrict__ key,
                                                const float* __restrict__ ce,
                                                int* cnt_i, float* cnt_f,
                                                unsigned* hist,
                                                float* __restrict__ out) {
    __shared__ unsigned lh[256];
    __shared__ unsigned sd[256];
    __shared__ float rs[256]; __shared__ int rc[256];
    int tid = threadIdx.x;
    int* bcnt = cnt_i + 32; int* bgen = cnt_i + 33;
    int stride4 = gridDim.x * 256;
    const uint4* k4 = (const uint4*)key;
    const int n4 = ROWS / 4;   // ROWS % 4 == 0

    for (int s = 0; s < 4; s++) {
        lh[tid] = 0; __syncthreads();
        unsigned prefix = (s == 0) ? 0u : (unsigned)cnt_i[8];  // post-fence normal load
        int shift = 24 - 8 * s;
        for (int i = blockIdx.x * 256 + tid; i < n4; i += stride4) {
            uint4 kk = k4[i];
            unsigned ka[4] = {kk.x, kk.y, kk.z, kk.w};
            #pragma unroll
            for (int j = 0; j < 4; j++) {
                unsigned k = ka[j];
                if (s == 0 || (k >> (shift + 8)) == prefix)
                    atomicAdd(&lh[(k >> shift) & 0xffu], 1u);
            }
        }
        __syncthreads();
        if (lh[tid]) atomicAdd(&hist[s * 256 + tid], lh[tid]);  // agent-scope RMW -> LLC
        grid_bar(bcnt, bgen);
        if (blockIdx.x == 0) {
            sd[tid] = hist[s * 256 + tid];
            __syncthreads();
            for (int off = 1; off < 256; off <<= 1) {
                unsigned add = (tid + off < 256) ? sd[tid + off] : 0u;
                __syncthreads();
                sd[tid] += add;
                __syncthreads();
            }
            unsigned Kr, pfx;
            if (s == 0) { Kr = 3u * (unsigned)cnt_i[0]; pfx = 0u; }
            else        { pfx = (unsigned)cnt_i[8]; Kr = (unsigned)cnt_i[9]; }
            unsigned cum = sd[tid];
            unsigned upper = (tid < 255) ? sd[tid + 1] : 0u;
            bool sel = (upper < Kr) && (cum >= Kr || tid == 0);
            if (sel) {
                unsigned np = (pfx << 8) | (unsigned)tid;
                unsigned nKr = Kr - upper;
                if (s < 3) {
                    __hip_atomic_store(&cnt_i[8], (int)np,  __ATOMIC_RELAXED, AGENT);
                    __hip_atomic_store(&cnt_i[9], (int)nKr, __ATOMIC_RELAXED, AGENT);
                } else {
                    __hip_atomic_store(&cnt_i[10], (int)np,  __ATOMIC_RELAXED, AGENT);
                    __hip_atomic_store(&cnt_i[11], (int)nKr, __ATOMIC_RELAXED, AGENT);
                }
            }
        }
        grid_bar(bcnt, bgen);
    }

    // negsum: key > T (key!=0 <=> candidate), or == T up to eqSlots.
    unsigned T = (unsigned)cnt_i[10];
    int eqS = cnt_i[11];
    float sacc = 0.f; int cacc = 0;
    for (int i = blockIdx.x * 256 + tid; i < n4; i += stride4) {
        uint4 kk = k4[i];
        unsigned ka[4] = {kk.x, kk.y, kk.z, kk.w};
        #pragma unroll
        for (int j = 0; j < 4; j++) {
            unsigned k = ka[j];
            if (k > T) { sacc += ce[4 * i + j]; cacc++; }
            else if (k == T && k != 0u) {
                int slot = atomicAdd(&cnt_i[5], 1);
                if (slot < eqS) { sacc += ce[4 * i + j]; cacc++; }
            }
        }
    }
    rs[tid] = sacc; rc[tid] = cacc; __syncthreads();
    for (int st = 128; st > 0; st >>= 1) {
        if (tid < st) { rs[tid] += rs[tid + st]; rc[tid] += rc[tid + st]; }
        __syncthreads();
    }
    if (tid == 0) {
        if (rs[0] != 0.f) atomicAdd(&cnt_f[3], rs[0]);
        if (rc[0])        atomicAdd(&cnt_i[4], rc[0]);
    }
    grid_bar(bcnt, bgen);
    if (blockIdx.x == 0 && tid == 0) {
        int np = cnt_i[0], nn = cnt_i[4];
        out[0] = cnt_f[1] / (float)max(np, 1);
        out[1] = (cnt_f[2] + cnt_f[3]) / (float)max(np + nn, 1);
    }
}

extern "C" void kernel_launch(void* const* d_in, const int* in_sizes, int n_in,
                              void* d_out, int out_size, void* d_ws, size_t ws_size,
                              hipStream_t stream) {
    const float* loc    = (const float*)d_in[0];
    const float* conf   = (const float*)d_in[1];
    const float* priors = (const float*)d_in[2];
    const float* gt     = (const float*)d_in[3];
    const int*   labels = (const int*)d_in[4];
    float* out = (float*)d_out;
    int*      wi = (int*)d_ws;
    float*    wf = (float*)d_ws;
    unsigned* wu = (unsigned*)d_ws;
    unsigned long long* wbp = (unsigned long long*)(wi + W_BP);

    hipMemsetAsync(d_ws, 0, 8192, stream);  // counters + hists + bp + barrier
    k_best_prior<<<dim3(NOBJ, BB, BPSPLIT), 256, 0, stream>>>(priors, gt, wbp);
    k_match<<<dim3((PP + 255) / 256, BB), 256, 0, stream>>>(
        loc, priors, gt, labels, wbp, wi + W_CONF, wf, wi);
    k_conf<<<CONF_GRID, 256, 0, stream>>>(conf, wi + W_CONF, wu + W_KEY, wf + W_CE, wf);
    k_select<<<SEL_GRID, 256, 0, stream>>>(
        wu + W_KEY, wf + W_CE, wi, wf, wu + W_HIST, out);
}

// Round 5
// 507.526 us; speedup vs baseline: 1.2108x; 1.0256x over previous
//
#include <hip/hip_runtime.h>
#include <math.h>

#define BB 8
#define PP 57744
#define NOBJ 20
#define CC 81
#define ROWS (BB*PP)
#define RPB 64                    // rows per tile in k_conf
#define TILE_F (RPB*CC)           // 5184 floats = 20736 B per tile
#define NT (ROWS/RPB)             // 7218 tiles
#define CONF_GRID 768             // 3 blocks/CU resident (LDS-bound), persistent
#define SEL_GRID 256              // <= #CUs: guaranteed co-resident for grid barrier
#define BPSPLIT 16
#define BPCHUNK ((PP + BPSPLIT - 1) / BPSPLIT)   // 3609

// ws layout in 4-byte units (first 8KB zeroed by memset)
// cnt_i: [0]=num_pos [1]=sl1_sum(f) [2]=pos_ce(f) [3]=neg_ce(f) [4]=neg_cnt [5]=eqCtr
//        [8]=prefix [9]=Kr [10]=T [11]=eqSlots [32]=bar_cnt [33]=bar_gen
#define W_HIST 64     // 4*256 bins
#define W_BP   1088   // 160 u64
#define W_CONF 2048           // ROWS ints
#define W_KEY  (2048 + ROWS)  // ROWS uints
#define W_CE   (2048 + 2*ROWS)// ROWS floats

#define AGENT __HIP_MEMORY_SCOPE_AGENT

__device__ __forceinline__ unsigned keymap(float f) {
    unsigned u = __float_as_uint(f);
    return (u & 0x80000000u) ? ~u : (u | 0x80000000u);
}

__device__ __forceinline__ float smooth_l1(float d) {
    float a = fabsf(d);
    return a < 1.f ? 0.5f * d * d : a - 0.5f;
}

// Grid barrier: RELAXED agent spin (LLC-coherent, no per-poll cache maintenance),
// one ACQ_REL RMW at arrival, one acquire fence at exit.
__device__ __forceinline__ void grid_bar(int* cnt, int* gen) {
    __syncthreads();
    if (threadIdx.x == 0) {
        int g = __hip_atomic_load(gen, __ATOMIC_RELAXED, AGENT);
        int old = __hip_atomic_fetch_add(cnt, 1, __ATOMIC_ACQ_REL, AGENT);
        if (old == (int)gridDim.x - 1) {
            __hip_atomic_store(cnt, 0, __ATOMIC_RELAXED, AGENT);
            __hip_atomic_store(gen, g + 1, __ATOMIC_RELEASE, AGENT);
        } else {
            while (__hip_atomic_load(gen, __ATOMIC_RELAXED, AGENT) == g)
                __builtin_amdgcn_s_sleep(2);
        }
        __builtin_amdgcn_fence(__ATOMIC_ACQUIRE, "agent");
    }
    __syncthreads();
}

// Grid (NOBJ, BB, BPSPLIT): per-(gt,batch) argmax over prior chunk, packed
// (iou_bits<<32)|(~p): u64 max == (max iou, lowest prior idx). IoU >= 0.
__global__ void k_best_prior(const float* __restrict__ priors,
                             const float* __restrict__ gt,
                             unsigned long long* __restrict__ bp) {
    int n = blockIdx.x, b = blockIdx.y;
    int p0 = blockIdx.z * BPCHUNK;
    int p1 = min(p0 + BPCHUNK, PP);
    const float* t = gt + (b * NOBJ + n) * 4;
    float tx1 = t[0], ty1 = t[1], tx2 = t[2], ty2 = t[3];
    float ta = (tx2 - tx1) * (ty2 - ty1);
    unsigned long long best = 0ull;
    for (int p = p0 + threadIdx.x; p < p1; p += 256) {
        float4 pr = ((const float4*)priors)[p];
        float px1 = pr.x - pr.z * 0.5f, py1 = pr.y - pr.w * 0.5f;
        float px2 = pr.x + pr.z * 0.5f, py2 = pr.y + pr.w * 0.5f;
        float iw = fmaxf(fminf(tx2, px2) - fmaxf(tx1, px1), 0.f);
        float ih = fmaxf(fminf(ty2, py2) - fmaxf(ty1, py1), 0.f);
        float inter = iw * ih;
        float iou = inter / (ta + (px2 - px1) * (py2 - py1) - inter);
        unsigned long long pk = ((unsigned long long)__float_as_uint(iou) << 32)
                              | (unsigned long long)(0xFFFFFFFFu - (unsigned)p);
        if (pk > best) best = pk;
    }
    __shared__ unsigned long long sb[256];
    int tid = threadIdx.x;
    sb[tid] = best; __syncthreads();
    for (int s = 128; s > 0; s >>= 1) {
        if (tid < s && sb[tid + s] > sb[tid]) sb[tid] = sb[tid + s];
        __syncthreads();
    }
    if (tid == 0) atomicMax(&bp[b * NOBJ + n], sb[0]);
}

__global__ void k_match(const float* __restrict__ loc_data,
                        const float* __restrict__ priors,
                        const float* __restrict__ gt,
                        const int* __restrict__ labels,
                        const unsigned long long* __restrict__ bp,
                        int* __restrict__ conf_t,
                        float* __restrict__ cnt_f,
                        int* __restrict__ cnt_i) {
    int b = blockIdx.y;
    int tid = threadIdx.x;
    int p = blockIdx.x * 256 + tid;
    __shared__ float st[NOBJ][4];
    __shared__ int slab[NOBJ], sbp[NOBJ];
    if (tid < NOBJ * 4) ((float*)st)[tid] = gt[b * NOBJ * 4 + tid];
    if (tid < NOBJ) {
        slab[tid] = labels[b * NOBJ + tid];
        sbp[tid] = (int)(0xFFFFFFFFu - (unsigned)bp[b * NOBJ + tid]);
    }
    __syncthreads();
    float s_l1 = 0.f; int is_pos = 0;
    if (p < PP) {
        float4 pr = ((const float4*)priors)[p];
        float px1 = pr.x - pr.z * 0.5f, py1 = pr.y - pr.w * 0.5f;
        float px2 = pr.x + pr.z * 0.5f, py2 = pr.y + pr.w * 0.5f;
        float pa = (px2 - px1) * (py2 - py1);
        float best = -1.f; int bn = 0;
        for (int n = 0; n < NOBJ; n++) {
            float tx1 = st[n][0], ty1 = st[n][1], tx2 = st[n][2], ty2 = st[n][3];
            float iw = fmaxf(fminf(tx2, px2) - fmaxf(tx1, px1), 0.f);
            float ih = fmaxf(fminf(ty2, py2) - fmaxf(ty1, py1), 0.f);
            float inter = iw * ih;
            float iou = inter / ((tx2 - tx1) * (ty2 - ty1) + pa - inter);
            if (iou > best) { best = iou; bn = n; }  // tie -> first n
        }
        float ov = best;
        for (int n = 0; n < NOBJ; n++)
            if (sbp[n] == p) { bn = n; ov = 2.0f; }  // last n wins
        int conf = slab[bn];
        if (ov < 0.5f) conf = -1;
        if (ov < 0.4f) conf = 0;
        conf_t[b * PP + p] = conf;
        if (conf > 0) {
            is_pos = 1;
            float mx1 = st[bn][0], my1 = st[bn][1], mx2 = st[bn][2], my2 = st[bn][3];
            float gcx = ((mx1 + mx2) * 0.5f - pr.x) / (0.1f * pr.z);
            float gcy = ((my1 + my2) * 0.5f - pr.y) / (0.1f * pr.w);
            float gw = logf((mx2 - mx1) / pr.z) / 0.2f;
            float gh = logf((my2 - my1) / pr.w) / 0.2f;
            float4 ld = ((const float4*)loc_data)[b * PP + p];
            s_l1 = smooth_l1(ld.x - gcx) + smooth_l1(ld.y - gcy) +
                   smooth_l1(ld.z - gw) + smooth_l1(ld.w - gh);
        }
    }
    __shared__ float rs[256]; __shared__ int rc[256];
    rs[tid] = s_l1; rc[tid] = is_pos; __syncthreads();
    for (int s = 128; s > 0; s >>= 1) {
        if (tid < s) { rs[tid] += rs[tid + s]; rc[tid] += rc[tid + s]; }
        __syncthreads();
    }
    if (tid == 0) {
        if (rs[0] != 0.f) atomicAdd(&cnt_f[1], rs[0]);
        if (rc[0])        atomicAdd(&cnt_i[0], rc[0]);
    }
}

// Persistent conf pass, async DMA double-buffer: global_load_lds (width 16)
// stages tile t+1 into the other LDS buffer right after the barrier, then
// tile t is computed from LDS. No VGPR staging -> nothing to spill.
__global__ void __launch_bounds__(256) k_conf(const float* __restrict__ conf_data,
                                              const int* __restrict__ conf_t,
                                              unsigned* __restrict__ key,
                                              float* __restrict__ ce,
                                              float* __restrict__ cnt_f) {
    __shared__ float sx[2][TILE_F];   // 2 x 20736 B -> 3 blocks/CU
    int tid = threadIdx.x;
    int wave = tid >> 6, lane = tid & 63;
    int r = tid >> 2, t = tid & 3;
    const float LOG2E = 1.4426950408889634f;

    // Stage one 20736B tile: 20 chunks of 64 lanes x 16B + 1 chunk of 64 x 4B.
    // LDS dest is wave-uniform base + lane*size (HW rule), layout contiguous.
    auto stage = [&](int tile, int buf) {
        const float* gbase = conf_data + (size_t)tile * TILE_F;
        float* lbase = &sx[buf][0];
        #pragma unroll
        for (int q = 0; q < 5; q++) {
            int c = q * 4 + wave;     // wave-uniform chunk id
            __builtin_amdgcn_global_load_lds(
                (const __attribute__((address_space(1))) void*)(gbase + c * 256 + lane * 4),
                (__attribute__((address_space(3))) void*)(lbase + c * 256), 16, 0, 0);
        }
        if (wave == 0)
            __builtin_amdgcn_global_load_lds(
                (const __attribute__((address_space(1))) void*)(gbase + 5120 + lane),
                (__attribute__((address_space(3))) void*)(lbase + 5120), 4, 0, 0);
    };

    int tile = blockIdx.x;
    stage(tile, 0);                   // prologue
    int buf = 0;
    for (; tile < NT; tile += CONF_GRID, buf ^= 1) {
        __syncthreads();              // vmcnt(0) drain: buf's DMA landed
        int nxt = tile + CONF_GRID;
        if (nxt < NT) stage(nxt, buf ^ 1);   // in flight across compute below
        const float* x = &sx[buf][r * CC];
        int row = tile * RPB + r;
        float m = (t == 0) ? x[0] : -INFINITY;
        float fg = -INFINITY;
        for (int c = (t == 0) ? 4 : t; c < CC; c += 4) {
            float v = x[c];
            m = fmaxf(m, v);
            fg = fmaxf(fg, v);
        }
        m = fmaxf(m, __shfl_xor(m, 1));
        m = fmaxf(m, __shfl_xor(m, 2));
        fg = fmaxf(fg, __shfl_xor(fg, 1));
        fg = fmaxf(fg, __shfl_xor(fg, 2));
        float e = 0.f;
        for (int c = t; c < CC; c += 4) e += exp2f((x[c] - m) * LOG2E);
        e += __shfl_xor(e, 1);
        e += __shfl_xor(e, 2);
        if (t == 0) {
            float lse = m + log2f(e) * 0.6931471805599453f;
            int ct = conf_t[row];
            int ctc = min(max(ct, 0), CC - 1);
            float cev = lse - x[ctc];
            ce[row] = cev;
            key[row] = (ct == 0) ? keymap(fg) : 0u;
            if (ct > 0) atomicAdd(&cnt_f[2], cev);
        }
    }
}

// Fused radix-select (4x hist+scan, 8-bit digits, LDS-privatized histograms)
// + negative CE sum + final. One dispatch, 9 grid barriers.
__global__ void __launch_bounds__(256) k_select(const unsigned* __restrict__ key,
                                                const float* __restrict__ ce,
                                                int* cnt_i, float* cnt_f,
                                                unsigned* hist,
                                                float* __restrict__ out) {
    __shared__ unsigned lh[256];
    __shared__ unsigned sd[256];
    __shared__ float rs[256]; __shared__ int rc[256];
    int tid = threadIdx.x;
    int* bcnt = cnt_i + 32; int* bgen = cnt_i + 33;
    int stride4 = gridDim.x * 256;
    const uint4* k4 = (const uint4*)key;
    const int n4 = ROWS / 4;   // ROWS % 4 == 0

    for (int s = 0; s < 4; s++) {
        lh[tid] = 0; __syncthreads();
        unsigned prefix = (s == 0) ? 0u : (unsigned)cnt_i[8];  // post-fence normal load
        int shift = 24 - 8 * s;
        for (int i = blockIdx.x * 256 + tid; i < n4; i += stride4) {
            uint4 kk = k4[i];
            unsigned ka[4] = {kk.x, kk.y, kk.z, kk.w};
            #pragma unroll
            for (int j = 0; j < 4; j++) {
                unsigned k = ka[j];
                if (s == 0 || (k >> (shift + 8)) == prefix)
                    atomicAdd(&lh[(k >> shift) & 0xffu], 1u);
            }
        }
        __syncthreads();
        if (lh[tid]) atomicAdd(&hist[s * 256 + tid], lh[tid]);  // agent-scope RMW -> LLC
        grid_bar(bcnt, bgen);
        if (blockIdx.x == 0) {
            sd[tid] = hist[s * 256 + tid];
            __syncthreads();
            for (int off = 1; off < 256; off <<= 1) {
                unsigned add = (tid + off < 256) ? sd[tid + off] : 0u;
                __syncthreads();
                sd[tid] += add;
                __syncthreads();
            }
            unsigned Kr, pfx;
            if (s == 0) { Kr = 3u * (unsigned)cnt_i[0]; pfx = 0u; }
            else        { pfx = (unsigned)cnt_i[8]; Kr = (unsigned)cnt_i[9]; }
            unsigned cum = sd[tid];
            unsigned upper = (tid < 255) ? sd[tid + 1] : 0u;
            bool sel = (upper < Kr) && (cum >= Kr || tid == 0);
            if (sel) {
                unsigned np = (pfx << 8) | (unsigned)tid;
                unsigned nKr = Kr - upper;
                if (s < 3) {
                    __hip_atomic_store(&cnt_i[8], (int)np,  __ATOMIC_RELAXED, AGENT);
                    __hip_atomic_store(&cnt_i[9], (int)nKr, __ATOMIC_RELAXED, AGENT);
                } else {
                    __hip_atomic_store(&cnt_i[10], (int)np,  __ATOMIC_RELAXED, AGENT);
                    __hip_atomic_store(&cnt_i[11], (int)nKr, __ATOMIC_RELAXED, AGENT);
                }
            }
        }
        grid_bar(bcnt, bgen);
    }

    // negsum: key > T (key!=0 <=> candidate), or == T up to eqSlots.
    unsigned T = (unsigned)cnt_i[10];
    int eqS = cnt_i[11];
    float sacc = 0.f; int cacc = 0;
    for (int i = blockIdx.x * 256 + tid; i < n4; i += stride4) {
        uint4 kk = k4[i];
        unsigned ka[4] = {kk.x, kk.y, kk.z, kk.w};
        #pragma unroll
        for (int j = 0; j < 4; j++) {
            unsigned k = ka[j];
            if (k > T) { sacc += ce[4 * i + j]; cacc++; }
            else if (k == T && k != 0u) {
                int slot = atomicAdd(&cnt_i[5], 1);
                if (slot < eqS) { sacc += ce[4 * i + j]; cacc++; }
            }
        }
    }
    rs[tid] = sacc; rc[tid] = cacc; __syncthreads();
    for (int st = 128; st > 0; st >>= 1) {
        if (tid < st) { rs[tid] += rs[tid + st]; rc[tid] += rc[tid + st]; }
        __syncthreads();
    }
    if (tid == 0) {
        if (rs[0] != 0.f) atomicAdd(&cnt_f[3], rs[0]);
        if (rc[0])        atomicAdd(&cnt_i[4], rc[0]);
    }
    grid_bar(bcnt, bgen);
    if (blockIdx.x == 0 && tid == 0) {
        int np = cnt_i[0], nn = cnt_i[4];
        out[0] = cnt_f[1] / (float)max(np, 1);
        out[1] = (cnt_f[2] + cnt_f[3]) / (float)max(np + nn, 1);
    }
}

extern "C" void kernel_launch(void* const* d_in, const int* in_sizes, int n_in,
                              void* d_out, int out_size, void* d_ws, size_t ws_size,
                              hipStream_t stream) {
    const float* loc    = (const float*)d_in[0];
    const float* conf   = (const float*)d_in[1];
    const float* priors = (const float*)d_in[2];
    const float* gt     = (const float*)d_in[3];
    const int*   labels = (const int*)d_in[4];
    float* out = (float*)d_out;
    int*      wi = (int*)d_ws;
    float*    wf = (float*)d_ws;
    unsigned* wu = (unsigned*)d_ws;
    unsigned long long* wbp = (unsigned long long*)(wi + W_BP);

    hipMemsetAsync(d_ws, 0, 8192, stream);  // counters + hists + bp + barrier
    k_best_prior<<<dim3(NOBJ, BB, BPSPLIT), 256, 0, stream>>>(priors, gt, wbp);
    k_match<<<dim3((PP + 255) / 256, BB), 256, 0, stream>>>(
        loc, priors, gt, labels, wbp, wi + W_CONF, wf, wi);
    k_conf<<<CONF_GRID, 256, 0, stream>>>(conf, wi + W_CONF, wu + W_KEY, wf + W_CE, wf);
    k_select<<<SEL_GRID, 256, 0, stream>>>(
        wu + W_KEY, wf + W_CE, wi, wf, wu + W_HIST, out);
}

// Round 6
// 506.961 us; speedup vs baseline: 1.2122x; 1.0011x over previous
//
#include <hip/hip_runtime.h>
#include <math.h>

#define BB 8
#define PP 57744
#define NOBJ 20
#define CC 81
#define ROWS (BB*PP)
#define SEL_GRID 256              // <= #CUs: guaranteed co-resident for grid barrier
#define BPSPLIT 16
#define BPCHUNK ((PP + BPSPLIT - 1) / BPSPLIT)   // 3609

// ws layout in 4-byte units (first 8KB zeroed by memset)
// cnt_i: [0]=num_pos [1]=sl1_sum(f) [2]=pos_ce(f) [3]=neg_ce(f) [4]=neg_cnt [5]=eqCtr
//        [8]=prefix [9]=Kr [10]=T [11]=eqSlots [32]=bar_cnt [33]=bar_gen
#define W_HIST 64     // 4*256 bins
#define W_BP   1088   // 160 u64
#define W_CONF 2048           // ROWS ints
#define W_KEY  (2048 + ROWS)  // ROWS uints
#define W_CE   (2048 + 2*ROWS)// ROWS floats

#define AGENT __HIP_MEMORY_SCOPE_AGENT

// float4 with 4-byte alignment: rows are 324 B so quarter-row starts are only
// dword-aligned; gfx950 unaligned-access mode still emits global_load_dwordx4.
typedef float f4a __attribute__((ext_vector_type(4), aligned(4)));

__device__ __forceinline__ unsigned keymap(float f) {
    unsigned u = __float_as_uint(f);
    return (u & 0x80000000u) ? ~u : (u | 0x80000000u);
}

__device__ __forceinline__ float smooth_l1(float d) {
    float a = fabsf(d);
    return a < 1.f ? 0.5f * d * d : a - 0.5f;
}

// Grid barrier: RELAXED agent spin (LLC-coherent, no per-poll cache maintenance),
// one ACQ_REL RMW at arrival, one acquire fence at exit.
__device__ __forceinline__ void grid_bar(int* cnt, int* gen) {
    __syncthreads();
    if (threadIdx.x == 0) {
        int g = __hip_atomic_load(gen, __ATOMIC_RELAXED, AGENT);
        int old = __hip_atomic_fetch_add(cnt, 1, __ATOMIC_ACQ_REL, AGENT);
        if (old == (int)gridDim.x - 1) {
            __hip_atomic_store(cnt, 0, __ATOMIC_RELAXED, AGENT);
            __hip_atomic_store(gen, g + 1, __ATOMIC_RELEASE, AGENT);
        } else {
            while (__hip_atomic_load(gen, __ATOMIC_RELAXED, AGENT) == g)
                __builtin_amdgcn_s_sleep(2);
        }
        __builtin_amdgcn_fence(__ATOMIC_ACQUIRE, "agent");
    }
    __syncthreads();
}

// Grid (NOBJ, BB, BPSPLIT): per-(gt,batch) argmax over prior chunk, packed
// (iou_bits<<32)|(~p): u64 max == (max iou, lowest prior idx). IoU >= 0.
__global__ void k_best_prior(const float* __restrict__ priors,
                             const float* __restrict__ gt,
                             unsigned long long* __restrict__ bp) {
    int n = blockIdx.x, b = blockIdx.y;
    int p0 = blockIdx.z * BPCHUNK;
    int p1 = min(p0 + BPCHUNK, PP);
    const float* t = gt + (b * NOBJ + n) * 4;
    float tx1 = t[0], ty1 = t[1], tx2 = t[2], ty2 = t[3];
    float ta = (tx2 - tx1) * (ty2 - ty1);
    unsigned long long best = 0ull;
    for (int p = p0 + threadIdx.x; p < p1; p += 256) {
        float4 pr = ((const float4*)priors)[p];
        float px1 = pr.x - pr.z * 0.5f, py1 = pr.y - pr.w * 0.5f;
        float px2 = pr.x + pr.z * 0.5f, py2 = pr.y + pr.w * 0.5f;
        float iw = fmaxf(fminf(tx2, px2) - fmaxf(tx1, px1), 0.f);
        float ih = fmaxf(fminf(ty2, py2) - fmaxf(ty1, py1), 0.f);
        float inter = iw * ih;
        float iou = inter / (ta + (px2 - px1) * (py2 - py1) - inter);
        unsigned long long pk = ((unsigned long long)__float_as_uint(iou) << 32)
                              | (unsigned long long)(0xFFFFFFFFu - (unsigned)p);
        if (pk > best) best = pk;
    }
    __shared__ unsigned long long sb[256];
    int tid = threadIdx.x;
    sb[tid] = best; __syncthreads();
    for (int s = 128; s > 0; s >>= 1) {
        if (tid < s && sb[tid + s] > sb[tid]) sb[tid] = sb[tid + s];
        __syncthreads();
    }
    if (tid == 0) atomicMax(&bp[b * NOBJ + n], sb[0]);
}

__global__ void k_match(const float* __restrict__ loc_data,
                        const float* __restrict__ priors,
                        const float* __restrict__ gt,
                        const int* __restrict__ labels,
                        const unsigned long long* __restrict__ bp,
                        int* __restrict__ conf_t,
                        float* __restrict__ cnt_f,
                        int* __restrict__ cnt_i) {
    int b = blockIdx.y;
    int tid = threadIdx.x;
    int p = blockIdx.x * 256 + tid;
    __shared__ float st[NOBJ][4];
    __shared__ int slab[NOBJ], sbp[NOBJ];
    if (tid < NOBJ * 4) ((float*)st)[tid] = gt[b * NOBJ * 4 + tid];
    if (tid < NOBJ) {
        slab[tid] = labels[b * NOBJ + tid];
        sbp[tid] = (int)(0xFFFFFFFFu - (unsigned)bp[b * NOBJ + tid]);
    }
    __syncthreads();
    float s_l1 = 0.f; int is_pos = 0;
    if (p < PP) {
        float4 pr = ((const float4*)priors)[p];
        float px1 = pr.x - pr.z * 0.5f, py1 = pr.y - pr.w * 0.5f;
        float px2 = pr.x + pr.z * 0.5f, py2 = pr.y + pr.w * 0.5f;
        float pa = (px2 - px1) * (py2 - py1);
        float best = -1.f; int bn = 0;
        for (int n = 0; n < NOBJ; n++) {
            float tx1 = st[n][0], ty1 = st[n][1], tx2 = st[n][2], ty2 = st[n][3];
            float iw = fmaxf(fminf(tx2, px2) - fmaxf(tx1, px1), 0.f);
            float ih = fmaxf(fminf(ty2, py2) - fmaxf(ty1, py1), 0.f);
            float inter = iw * ih;
            float iou = inter / ((tx2 - tx1) * (ty2 - ty1) + pa - inter);
            if (iou > best) { best = iou; bn = n; }  // tie -> first n
        }
        float ov = best;
        for (int n = 0; n < NOBJ; n++)
            if (sbp[n] == p) { bn = n; ov = 2.0f; }  // last n wins
        int conf = slab[bn];
        if (ov < 0.5f) conf = -1;
        if (ov < 0.4f) conf = 0;
        conf_t[b * PP + p] = conf;
        if (conf > 0) {
            is_pos = 1;
            float mx1 = st[bn][0], my1 = st[bn][1], mx2 = st[bn][2], my2 = st[bn][3];
            float gcx = ((mx1 + mx2) * 0.5f - pr.x) / (0.1f * pr.z);
            float gcy = ((my1 + my2) * 0.5f - pr.y) / (0.1f * pr.w);
            float gw = logf((mx2 - mx1) / pr.z) / 0.2f;
            float gh = logf((my2 - my1) / pr.w) / 0.2f;
            float4 ld = ((const float4*)loc_data)[b * PP + p];
            s_l1 = smooth_l1(ld.x - gcx) + smooth_l1(ld.y - gcy) +
                   smooth_l1(ld.z - gw) + smooth_l1(ld.w - gh);
        }
    }
    __shared__ float rs[256]; __shared__ int rc[256];
    rs[tid] = s_l1; rc[tid] = is_pos; __syncthreads();
    for (int s = 128; s > 0; s >>= 1) {
        if (tid < s) { rs[tid] += rs[tid + s]; rc[tid] += rc[tid + s]; }
        __syncthreads();
    }
    if (tid == 0) {
        if (rs[0] != 0.f) atomicAdd(&cnt_f[1], rs[0]);
        if (rc[0])        atomicAdd(&cnt_i[0], rc[0]);
    }
}

// Conf pass, register-direct: 4 threads/row, each loads its 20-float quarter
// row straight from global (5x dwordx4) into a fully-unrolled register array.
// No LDS, no barriers, no dependent scalar reads; width-4 shuffle reductions.
__global__ void __launch_bounds__(256) k_conf(const float* __restrict__ conf_data,
                                              const int* __restrict__ conf_t,
                                              unsigned* __restrict__ key,
                                              float* __restrict__ ce,
                                              float* __restrict__ cnt_f) {
    int tid = threadIdx.x;
    int r = tid >> 2, t = tid & 3;
    int row = blockIdx.x * 64 + r;
    const float* xg = conf_data + (size_t)row * CC + t * 20;
    const float LOG2E = 1.4426950408889634f;

    float xr[20];
    #pragma unroll
    for (int i = 0; i < 5; i++) {
        f4a v = ((const f4a*)xg)[i];
        xr[4 * i + 0] = v.x; xr[4 * i + 1] = v.y;
        xr[4 * i + 2] = v.z; xr[4 * i + 3] = v.w;
    }
    float x80 = (t == 3) ? conf_data[(size_t)row * CC + 80] : -INFINITY;
    int ct = conf_t[row];
    int ctc = min(max(ct, 0), CC - 1);

    float m = -INFINITY, fg = -INFINITY, xct = -INFINITY;
    #pragma unroll
    for (int i = 0; i < 20; i++) {
        int c = t * 20 + i;
        float v = xr[i];
        m = fmaxf(m, v);
        fg = (c >= 1) ? fmaxf(fg, v) : fg;
        xct = (c == ctc) ? v : xct;
    }
    m = fmaxf(m, x80);                       // t==3 contributes class 80
    fg = fmaxf(fg, x80);
    xct = (t == 3 && ctc == 80) ? x80 : xct;

    m = fmaxf(m, __shfl_xor(m, 1));
    m = fmaxf(m, __shfl_xor(m, 2));
    fg = fmaxf(fg, __shfl_xor(fg, 1));
    fg = fmaxf(fg, __shfl_xor(fg, 2));
    xct = fmaxf(xct, __shfl_xor(xct, 1));
    xct = fmaxf(xct, __shfl_xor(xct, 2));

    float e = exp2f((x80 - m) * LOG2E);      // exp2(-inf)=0 for t!=3
    #pragma unroll
    for (int i = 0; i < 20; i++) e += exp2f((xr[i] - m) * LOG2E);
    e += __shfl_xor(e, 1);
    e += __shfl_xor(e, 2);

    if (t == 0) {
        float lse = m + log2f(e) * 0.6931471805599453f;
        float cev = lse - xct;
        ce[row] = cev;
        key[row] = (ct == 0) ? keymap(fg) : 0u;
        if (ct > 0) atomicAdd(&cnt_f[2], cev);
    }
}

// Fused radix-select (4x hist+scan, 8-bit digits, LDS-privatized histograms)
// + negative CE sum + final. One dispatch, 9 grid barriers.
__global__ void __launch_bounds__(256) k_select(const unsigned* __restrict__ key,
                                                const float* __restrict__ ce,
                                                int* cnt_i, float* cnt_f,
                                                unsigned* hist,
                                                float* __restrict__ out) {
    __shared__ unsigned lh[256];
    __shared__ unsigned sd[256];
    __shared__ float rs[256]; __shared__ int rc[256];
    int tid = threadIdx.x;
    int* bcnt = cnt_i + 32; int* bgen = cnt_i + 33;
    int stride4 = gridDim.x * 256;
    const uint4* k4 = (const uint4*)key;
    const int n4 = ROWS / 4;   // ROWS % 4 == 0

    for (int s = 0; s < 4; s++) {
        lh[tid] = 0; __syncthreads();
        unsigned prefix = (s == 0) ? 0u : (unsigned)cnt_i[8];  // post-fence normal load
        int shift = 24 - 8 * s;
        for (int i = blockIdx.x * 256 + tid; i < n4; i += stride4) {
            uint4 kk = k4[i];
            unsigned ka[4] = {kk.x, kk.y, kk.z, kk.w};
            #pragma unroll
            for (int j = 0; j < 4; j++) {
                unsigned k = ka[j];
                if (s == 0 || (k >> (shift + 8)) == prefix)
                    atomicAdd(&lh[(k >> shift) & 0xffu], 1u);
            }
        }
        __syncthreads();
        if (lh[tid]) atomicAdd(&hist[s * 256 + tid], lh[tid]);  // agent-scope RMW -> LLC
        grid_bar(bcnt, bgen);
        if (blockIdx.x == 0) {
            sd[tid] = hist[s * 256 + tid];
            __syncthreads();
            for (int off = 1; off < 256; off <<= 1) {
                unsigned add = (tid + off < 256) ? sd[tid + off] : 0u;
                __syncthreads();
                sd[tid] += add;
                __syncthreads();
            }
            unsigned Kr, pfx;
            if (s == 0) { Kr = 3u * (unsigned)cnt_i[0]; pfx = 0u; }
            else        { pfx = (unsigned)cnt_i[8]; Kr = (unsigned)cnt_i[9]; }
            unsigned cum = sd[tid];
            unsigned upper = (tid < 255) ? sd[tid + 1] : 0u;
            bool sel = (upper < Kr) && (cum >= Kr || tid == 0);
            if (sel) {
                unsigned np = (pfx << 8) | (unsigned)tid;
                unsigned nKr = Kr - upper;
                if (s < 3) {
                    __hip_atomic_store(&cnt_i[8], (int)np,  __ATOMIC_RELAXED, AGENT);
                    __hip_atomic_store(&cnt_i[9], (int)nKr, __ATOMIC_RELAXED, AGENT);
                } else {
                    __hip_atomic_store(&cnt_i[10], (int)np,  __ATOMIC_RELAXED, AGENT);
                    __hip_atomic_store(&cnt_i[11], (int)nKr, __ATOMIC_RELAXED, AGENT);
                }
            }
        }
        grid_bar(bcnt, bgen);
    }

    // negsum: key > T (key!=0 <=> candidate), or == T up to eqSlots.
    unsigned T = (unsigned)cnt_i[10];
    int eqS = cnt_i[11];
    float sacc = 0.f; int cacc = 0;
    for (int i = blockIdx.x * 256 + tid; i < n4; i += stride4) {
        uint4 kk = k4[i];
        unsigned ka[4] = {kk.x, kk.y, kk.z, kk.w};
        #pragma unroll
        for (int j = 0; j < 4; j++) {
            unsigned k = ka[j];
            if (k > T) { sacc += ce[4 * i + j]; cacc++; }
            else if (k == T && k != 0u) {
                int slot = atomicAdd(&cnt_i[5], 1);
                if (slot < eqS) { sacc += ce[4 * i + j]; cacc++; }
            }
        }
    }
    rs[tid] = sacc; rc[tid] = cacc; __syncthreads();
    for (int st = 128; st > 0; st >>= 1) {
        if (tid < st) { rs[tid] += rs[tid + st]; rc[tid] += rc[tid + st]; }
        __syncthreads();
    }
    if (tid == 0) {
        if (rs[0] != 0.f) atomicAdd(&cnt_f[3], rs[0]);
        if (rc[0])        atomicAdd(&cnt_i[4], rc[0]);
    }
    grid_bar(bcnt, bgen);
    if (blockIdx.x == 0 && tid == 0) {
        int np = cnt_i[0], nn = cnt_i[4];
        out[0] = cnt_f[1] / (float)max(np, 1);
        out[1] = (cnt_f[2] + cnt_f[3]) / (float)max(np + nn, 1);
    }
}

extern "C" void kernel_launch(void* const* d_in, const int* in_sizes, int n_in,
                              void* d_out, int out_size, void* d_ws, size_t ws_size,
                              hipStream_t stream) {
    const float* loc    = (const float*)d_in[0];
    const float* conf   = (const float*)d_in[1];
    const float* priors = (const float*)d_in[2];
    const float* gt     = (const float*)d_in[3];
    const int*   labels = (const int*)d_in[4];
    float* out = (float*)d_out;
    int*      wi = (int*)d_ws;
    float*    wf = (float*)d_ws;
    unsigned* wu = (unsigned*)d_ws;
    unsigned long long* wbp = (unsigned long long*)(wi + W_BP);

    hipMemsetAsync(d_ws, 0, 8192, stream);  // counters + hists + bp + barrier
    k_best_prior<<<dim3(NOBJ, BB, BPSPLIT), 256, 0, stream>>>(priors, gt, wbp);
    k_match<<<dim3((PP + 255) / 256, BB), 256, 0, stream>>>(
        loc, priors, gt, labels, wbp, wi + W_CONF, wf, wi);
    k_conf<<<ROWS / 64, 256, 0, stream>>>(conf, wi + W_CONF, wu + W_KEY, wf + W_CE, wf);
    k_select<<<SEL_GRID, 256, 0, stream>>>(
        wu + W_KEY, wf + W_CE, wi, wf, wu + W_HIST, out);
}

// Round 7
// 492.935 us; speedup vs baseline: 1.2467x; 1.0285x over previous
//
#include <hip/hip_runtime.h>
#include <math.h>

#define BB 8
#define PP 57744
#define NOBJ 20
#define CC 81
#define ROWS (BB*PP)
#define SEL_GRID 256              // <= #CUs: guaranteed co-resident for grid barrier
#define BPSPLIT 16
#define BPCHUNK ((PP + BPSPLIT - 1) / BPSPLIT)   // 3609

// ws layout in 4-byte units (first 8KB zeroed by memset)
// cnt_i: [0]=num_pos [1]=sl1_sum(f) [2]=pos_ce(f) [3]=neg_ce(f) [4]=neg_cnt [5]=eqCtr
//        [32]=bar_cnt [33]=bar_gen
#define W_HIST 64     // 4*256 bins
#define W_BP   1088   // 160 u64
#define W_CONF 2048           // ROWS ints
#define W_KEY  (2048 + ROWS)  // ROWS uints
#define W_CE   (2048 + 2*ROWS)// ROWS floats

#define AGENT __HIP_MEMORY_SCOPE_AGENT

// 16B vector with 4-byte alignment (rows are 324 B; quarter-row starts are
// only dword-aligned; gfx950 unaligned mode still emits dwordx4).
typedef float f4a __attribute__((ext_vector_type(4), aligned(4)));

__device__ __forceinline__ unsigned keymap(float f) {
    unsigned u = __float_as_uint(f);
    return (u & 0x80000000u) ? ~u : (u | 0x80000000u);
}

__device__ __forceinline__ float smooth_l1(float d) {
    float a = fabsf(d);
    return a < 1.f ? 0.5f * d * d : a - 0.5f;
}

// Grid barrier: RELAXED agent spin, one ACQ_REL RMW at arrival, one acquire
// fence at exit (invalidates L1/L2 so post-barrier plain loads are fresh).
__device__ __forceinline__ void grid_bar(int* cnt, int* gen) {
    __syncthreads();
    if (threadIdx.x == 0) {
        int g = __hip_atomic_load(gen, __ATOMIC_RELAXED, AGENT);
        int old = __hip_atomic_fetch_add(cnt, 1, __ATOMIC_ACQ_REL, AGENT);
        if (old == (int)gridDim.x - 1) {
            __hip_atomic_store(cnt, 0, __ATOMIC_RELAXED, AGENT);
            __hip_atomic_store(gen, g + 1, __ATOMIC_RELEASE, AGENT);
        } else {
            while (__hip_atomic_load(gen, __ATOMIC_RELAXED, AGENT) == g)
                __builtin_amdgcn_s_sleep(2);
        }
        __builtin_amdgcn_fence(__ATOMIC_ACQUIRE, "agent");
    }
    __syncthreads();
}

// Grid (NOBJ, BB, BPSPLIT): per-(gt,batch) argmax over prior chunk, packed
// (iou_bits<<32)|(~p): u64 max == (max iou, lowest prior idx). IoU >= 0.
__global__ void k_best_prior(const float* __restrict__ priors,
                             const float* __restrict__ gt,
                             unsigned long long* __restrict__ bp) {
    int n = blockIdx.x, b = blockIdx.y;
    int p0 = blockIdx.z * BPCHUNK;
    int p1 = min(p0 + BPCHUNK, PP);
    const float* t = gt + (b * NOBJ + n) * 4;
    float tx1 = t[0], ty1 = t[1], tx2 = t[2], ty2 = t[3];
    float ta = (tx2 - tx1) * (ty2 - ty1);
    unsigned long long best = 0ull;
    for (int p = p0 + threadIdx.x; p < p1; p += 256) {
        float4 pr = ((const float4*)priors)[p];
        float px1 = pr.x - pr.z * 0.5f, py1 = pr.y - pr.w * 0.5f;
        float px2 = pr.x + pr.z * 0.5f, py2 = pr.y + pr.w * 0.5f;
        float iw = fmaxf(fminf(tx2, px2) - fmaxf(tx1, px1), 0.f);
        float ih = fmaxf(fminf(ty2, py2) - fmaxf(ty1, py1), 0.f);
        float inter = iw * ih;
        float iou = inter / (ta + (px2 - px1) * (py2 - py1) - inter);
        unsigned long long pk = ((unsigned long long)__float_as_uint(iou) << 32)
                              | (unsigned long long)(0xFFFFFFFFu - (unsigned)p);
        if (pk > best) best = pk;
    }
    __shared__ unsigned long long sb[256];
    int tid = threadIdx.x;
    sb[tid] = best; __syncthreads();
    for (int s = 128; s > 0; s >>= 1) {
        if (tid < s && sb[tid + s] > sb[tid]) sb[tid] = sb[tid + s];
        __syncthreads();
    }
    if (tid == 0) atomicMax(&bp[b * NOBJ + n], sb[0]);
}

__global__ void k_match(const float* __restrict__ loc_data,
                        const float* __restrict__ priors,
                        const float* __restrict__ gt,
                        const int* __restrict__ labels,
                        const unsigned long long* __restrict__ bp,
                        int* __restrict__ conf_t,
                        float* __restrict__ cnt_f,
                        int* __restrict__ cnt_i) {
    int b = blockIdx.y;
    int tid = threadIdx.x;
    int p = blockIdx.x * 256 + tid;
    __shared__ float st[NOBJ][4];
    __shared__ int slab[NOBJ], sbp[NOBJ];
    if (tid < NOBJ * 4) ((float*)st)[tid] = gt[b * NOBJ * 4 + tid];
    if (tid < NOBJ) {
        slab[tid] = labels[b * NOBJ + tid];
        sbp[tid] = (int)(0xFFFFFFFFu - (unsigned)bp[b * NOBJ + tid]);
    }
    __syncthreads();
    float s_l1 = 0.f; int is_pos = 0;
    if (p < PP) {
        float4 pr = ((const float4*)priors)[p];
        float px1 = pr.x - pr.z * 0.5f, py1 = pr.y - pr.w * 0.5f;
        float px2 = pr.x + pr.z * 0.5f, py2 = pr.y + pr.w * 0.5f;
        float pa = (px2 - px1) * (py2 - py1);
        float best = -1.f; int bn = 0;
        for (int n = 0; n < NOBJ; n++) {
            float tx1 = st[n][0], ty1 = st[n][1], tx2 = st[n][2], ty2 = st[n][3];
            float iw = fmaxf(fminf(tx2, px2) - fmaxf(tx1, px1), 0.f);
            float ih = fmaxf(fminf(ty2, py2) - fmaxf(ty1, py1), 0.f);
            float inter = iw * ih;
            float iou = inter / ((tx2 - tx1) * (ty2 - ty1) + pa - inter);
            if (iou > best) { best = iou; bn = n; }  // tie -> first n
        }
        float ov = best;
        for (int n = 0; n < NOBJ; n++)
            if (sbp[n] == p) { bn = n; ov = 2.0f; }  // last n wins
        int conf = slab[bn];
        if (ov < 0.5f) conf = -1;
        if (ov < 0.4f) conf = 0;
        conf_t[b * PP + p] = conf;
        if (conf > 0) {
            is_pos = 1;
            float mx1 = st[bn][0], my1 = st[bn][1], mx2 = st[bn][2], my2 = st[bn][3];
            float gcx = ((mx1 + mx2) * 0.5f - pr.x) / (0.1f * pr.z);
            float gcy = ((my1 + my2) * 0.5f - pr.y) / (0.1f * pr.w);
            float gw = logf((mx2 - mx1) / pr.z) / 0.2f;
            float gh = logf((my2 - my1) / pr.w) / 0.2f;
            float4 ld = ((const float4*)loc_data)[b * PP + p];
            s_l1 = smooth_l1(ld.x - gcx) + smooth_l1(ld.y - gcy) +
                   smooth_l1(ld.z - gw) + smooth_l1(ld.w - gh);
        }
    }
    __shared__ float rs[256]; __shared__ int rc[256];
    rs[tid] = s_l1; rc[tid] = is_pos; __syncthreads();
    for (int s = 128; s > 0; s >>= 1) {
        if (tid < s) { rs[tid] += rs[tid + s]; rc[tid] += rc[tid + s]; }
        __syncthreads();
    }
    if (tid == 0) {
        if (rs[0] != 0.f) atomicAdd(&cnt_f[1], rs[0]);
        if (rc[0])        atomicAdd(&cnt_i[0], rc[0]);
    }
}

// Conf pass, register-direct + nontemporal + 2 rows/thread-group:
// 4 threads/row; each thread loads BOTH rows' 20-float quarters (10
// independent 16B NT loads in flight) before reducing either row.
__global__ void __launch_bounds__(256) k_conf(const float* __restrict__ conf_data,
                                              const int* __restrict__ conf_t,
                                              unsigned* __restrict__ key,
                                              float* __restrict__ ce,
                                              float* __restrict__ cnt_f) {
    int tid = threadIdx.x;
    int r = tid >> 2, t = tid & 3;
    int row0 = blockIdx.x * 128 + r;      // rows [blk*128+r] and [+64]
    int row1 = row0 + 64;
    const float LOG2E = 1.4426950408889634f;

    const f4a* g0 = (const f4a*)(conf_data + (size_t)row0 * CC + t * 20);
    const f4a* g1 = (const f4a*)(conf_data + (size_t)row1 * CC + t * 20);
    f4a v0[5], v1[5];
    #pragma unroll
    for (int i = 0; i < 5; i++) v0[i] = __builtin_nontemporal_load(g0 + i);
    #pragma unroll
    for (int i = 0; i < 5; i++) v1[i] = __builtin_nontemporal_load(g1 + i);
    float x80_0 = (t == 3) ? __builtin_nontemporal_load(conf_data + (size_t)row0 * CC + 80) : -INFINITY;
    float x80_1 = (t == 3) ? __builtin_nontemporal_load(conf_data + (size_t)row1 * CC + 80) : -INFINITY;
    int ct0 = conf_t[row0], ct1 = conf_t[row1];

    auto reduce_row = [&](const f4a* v, float x80, int ct, int row) {
        int ctc = min(max(ct, 0), CC - 1);
        float m = -INFINITY, fg = -INFINITY, xct = -INFINITY;
        float xr[20];
        #pragma unroll
        for (int i = 0; i < 5; i++) {
            xr[4*i+0] = v[i].x; xr[4*i+1] = v[i].y;
            xr[4*i+2] = v[i].z; xr[4*i+3] = v[i].w;
        }
        #pragma unroll
        for (int i = 0; i < 20; i++) {
            int c = t * 20 + i;
            float val = xr[i];
            m = fmaxf(m, val);
            fg = (c >= 1) ? fmaxf(fg, val) : fg;
            xct = (c == ctc) ? val : xct;
        }
        m = fmaxf(m, x80);
        fg = fmaxf(fg, x80);
        xct = (t == 3 && ctc == 80) ? x80 : xct;
        m = fmaxf(m, __shfl_xor(m, 1));
        m = fmaxf(m, __shfl_xor(m, 2));
        fg = fmaxf(fg, __shfl_xor(fg, 1));
        fg = fmaxf(fg, __shfl_xor(fg, 2));
        xct = fmaxf(xct, __shfl_xor(xct, 1));
        xct = fmaxf(xct, __shfl_xor(xct, 2));
        float e = exp2f((x80 - m) * LOG2E);
        #pragma unroll
        for (int i = 0; i < 20; i++) e += exp2f((xr[i] - m) * LOG2E);
        e += __shfl_xor(e, 1);
        e += __shfl_xor(e, 2);
        if (t == 0) {
            float lse = m + log2f(e) * 0.6931471805599453f;
            float cev = lse - xct;
            ce[row] = cev;
            key[row] = (ct == 0) ? keymap(fg) : 0u;
            if (ct > 0) atomicAdd(&cnt_f[2], cev);
        }
    };
    reduce_row(v0, x80_0, ct0, row0);
    reduce_row(v1, x80_1, ct1, row1);
}

// Fused radix-select + negsum + final. 5 grid barriers: every block
// redundantly computes the scan/digit-pick locally (prefix/Kr in registers).
__global__ void __launch_bounds__(256) k_select(const unsigned* __restrict__ key,
                                                const float* __restrict__ ce,
                                                int* cnt_i, float* cnt_f,
                                                unsigned* hist,
                                                float* __restrict__ out) {
    __shared__ unsigned lh[256];
    __shared__ unsigned sd[256];
    __shared__ unsigned spick, sKr;
    __shared__ float rs[256]; __shared__ int rc[256];
    int tid = threadIdx.x;
    int* bcnt = cnt_i + 32; int* bgen = cnt_i + 33;
    int stride4 = gridDim.x * 256;
    const uint4* k4 = (const uint4*)key;
    const int n4 = ROWS / 4;   // ROWS % 4 == 0

    unsigned prefix = 0u, Kr = 0u;   // identical in every block
    for (int s = 0; s < 4; s++) {
        lh[tid] = 0; __syncthreads();
        int shift = 24 - 8 * s;
        for (int i = blockIdx.x * 256 + tid; i < n4; i += stride4) {
            uint4 kk = k4[i];
            unsigned ka[4] = {kk.x, kk.y, kk.z, kk.w};
            #pragma unroll
            for (int j = 0; j < 4; j++) {
                unsigned k = ka[j];
                if (s == 0 || (k >> (shift + 8)) == prefix)
                    atomicAdd(&lh[(k >> shift) & 0xffu], 1u);
            }
        }
        __syncthreads();
        if (lh[tid]) atomicAdd(&hist[s * 256 + tid], lh[tid]);  // device RMW -> LLC
        grid_bar(bcnt, bgen);   // all hist atomics visible; caches invalidated
        if (s == 0) Kr = 3u * (unsigned)cnt_i[0];  // num_pos (post-fence load)
        // every block: suffix-scan the global hist locally, pick the digit
        sd[tid] = hist[s * 256 + tid];
        __syncthreads();
        for (int off = 1; off < 256; off <<= 1) {
            unsigned add = (tid + off < 256) ? sd[tid + off] : 0u;
            __syncthreads();
            sd[tid] += add;
            __syncthreads();
        }
        unsigned cum = sd[tid];
        unsigned upper = (tid < 255) ? sd[tid + 1] : 0u;
        if ((upper < Kr) && (cum >= Kr || tid == 0)) {
            spick = (unsigned)tid;
            sKr = Kr - upper;
        }
        __syncthreads();
        prefix = (prefix << 8) | spick;
        Kr = sKr;
        __syncthreads();
    }

    // negsum: key > T (key!=0 <=> candidate), or == T up to eqSlots.
    unsigned T = prefix;
    int eqS = (int)Kr;
    float sacc = 0.f; int cacc = 0;
    for (int i = blockIdx.x * 256 + tid; i < n4; i += stride4) {
        uint4 kk = k4[i];
        unsigned ka[4] = {kk.x, kk.y, kk.z, kk.w};
        #pragma unroll
        for (int j = 0; j < 4; j++) {
            unsigned k = ka[j];
            if (k > T) { sacc += ce[4 * i + j]; cacc++; }
            else if (k == T && k != 0u) {
                int slot = atomicAdd(&cnt_i[5], 1);
                if (slot < eqS) { sacc += ce[4 * i + j]; cacc++; }
            }
        }
    }
    rs[tid] = sacc; rc[tid] = cacc; __syncthreads();
    for (int st = 128; st > 0; st >>= 1) {
        if (tid < st) { rs[tid] += rs[tid + st]; rc[tid] += rc[tid + st]; }
        __syncthreads();
    }
    if (tid == 0) {
        if (rs[0] != 0.f) atomicAdd(&cnt_f[3], rs[0]);
        if (rc[0])        atomicAdd(&cnt_i[4], rc[0]);
    }
    grid_bar(bcnt, bgen);
    if (blockIdx.x == 0 && tid == 0) {
        int np = cnt_i[0], nn = cnt_i[4];
        out[0] = cnt_f[1] / (float)max(np, 1);
        out[1] = (cnt_f[2] + cnt_f[3]) / (float)max(np + nn, 1);
    }
}

extern "C" void kernel_launch(void* const* d_in, const int* in_sizes, int n_in,
                              void* d_out, int out_size, void* d_ws, size_t ws_size,
                              hipStream_t stream) {
    const float* loc    = (const float*)d_in[0];
    const float* conf   = (const float*)d_in[1];
    const float* priors = (const float*)d_in[2];
    const float* gt     = (const float*)d_in[3];
    const int*   labels = (const int*)d_in[4];
    float* out = (float*)d_out;
    int*      wi = (int*)d_ws;
    float*    wf = (float*)d_ws;
    unsigned* wu = (unsigned*)d_ws;
    unsigned long long* wbp = (unsigned long long*)(wi + W_BP);

    hipMemsetAsync(d_ws, 0, 8192, stream);  // counters + hists + bp + barrier
    k_best_prior<<<dim3(NOBJ, BB, BPSPLIT), 256, 0, stream>>>(priors, gt, wbp);
    k_match<<<dim3((PP + 255) / 256, BB), 256, 0, stream>>>(
        loc, priors, gt, labels, wbp, wi + W_CONF, wf, wi);
    k_conf<<<ROWS / 128, 256, 0, stream>>>(conf, wi + W_CONF, wu + W_KEY, wf + W_CE, wf);
    k_select<<<SEL_GRID, 256, 0, stream>>>(
        wu + W_KEY, wf + W_CE, wi, wf, wu + W_HIST, out);
}